// Round 4
// baseline (530.758 us; speedup 1.0000x reference)
//
#include <hip/hip_runtime.h>
#include <hip/hip_bf16.h>
#include <math.h>

#define NB 64          // batch
#define NS 4096        // seq
#define NC 21          // classes
#define NCC 441        // NC*NC
#define TSTEPS 200

typedef float vfloat4 __attribute__((ext_vector_type(4)));

// ws layout: float4 per batch: {qo, qd, Loff, Ldelta}
//   qo = (1-a)/21, qd = qo + a, Loff = log(qo+eps), Ldelta = log(qd+eps)-Loff

__global__ __launch_bounds__(64) void schedule_kernel(const int* __restrict__ t,
                                                      float4* __restrict__ ws) {
    int b = threadIdx.x;            // one batch per lane, single block of 64
    int tb = t[b];
    const float HPI = 1.5707963267948966f;
    const float P = 1e-4f;
    float cum = 1.0f;
    float alpha = 1.0f;
    float c0 = cosf(P / (1.0f + P) * HPI);             // cos at step 0 (libm for precision)
    for (int i = 0; i < TSTEPS; ++i) {
        float s1 = ((float)(i + 1) / (float)TSTEPS + P) / (1.0f + P) * HPI;
        float c1 = cosf(s1);
        float beta = 1.0f - (c1 * c1) / (c0 * c0);
        beta = fminf(fmaxf(beta, 0.0f), 0.999f);
        cum *= (1.0f - beta);
        if (i == tb) alpha = cum;   // no break: keep wave uniform
        c0 = c1;
    }
    float qo = (1.0f - alpha) / (float)NC;
    float qd = qo + alpha;
    float Loff  = logf(qo + 1e-10f);
    float Ldiag = logf(qd + 1e-10f);
    ws[b] = make_float4(qo, qd, Loff, Ldiag - Loff);
}

// Fused: 17408 blocks. Every 17th block (id%17==0: 1024 blocks) computes
// logits (256 rows each); the other 16384 stream q_t (1764 float4 each =
// 16 repeats of the 441-float 21x21 tile; each chunk starts at tile pos 0).
__global__ __launch_bounds__(256) void fused_kernel(const float* __restrict__ x0,
                                                    const float4* __restrict__ ws,
                                                    float* __restrict__ logits,
                                                    float* __restrict__ qt) {
    const int tid = threadIdx.x;
    const int id = blockIdx.x;
    const int div17 = id / 17;

    if (id % 17 != 0) {
        // ---------------- q_t path: register-direct, no LDS, no barriers ----
        const int blk = id - 1 - div17;          // 0..16383
        const int b = blk >> 8;                  // 256 chunks per batch
        const float4 w = ws[b];
        const float qo = w.x, qd = w.y;

        vfloat4* dst = (vfloat4*)qt + (size_t)blk * 1764;

        // pattern position of this thread's first float4: p = 4*tid mod 441
        int p = tid * 4;
        if (p >= 882) p -= 882;
        else if (p >= 441) p -= 441;
        int r = p % 22;                          // p mod 22 (diag iff pos%22==0)

#pragma unroll
        for (int k = 0; k < 7; ++k) {
            const int idx = tid + k * 256;
            vfloat4 v;
#pragma unroll
            for (int m = 0; m < 4; ++m) {
                const int pm = p + m;
                const int rm = r + m;
                // wrapped element: pos = pm-441 in [0,3], diag iff pm==441
                const bool diag = (pm >= 441) ? (pm == 441) : (rm == 0 || rm == 22);
                v[m] = diag ? qd : qo;
            }
            if (idx < 1764) __builtin_nontemporal_store(v, &dst[idx]);
            // advance 256 float4 = 1024 floats: +142 mod 441, +10 mod 22;
            // the 441-wrap subtracts 441 ≡ 1 (mod 22) from r.
            p += 142; r += 10;
            if (p >= 441) { p -= 441; r -= 1; }
            if (r >= 22) r -= 22;
        }
    } else {
        // ---------------- logits path ----------------
        __shared__ float4 s4[1344];               // 21.5 KB
        const int blk = div17;                    // 0..1023, 256 rows each
        const int b = blk >> 4;                   // 16 blocks per batch
        const float4 w = ws[b];
        const float Loff = w.z, Ldelta = w.w;

        const float4* g = (const float4*)x0 + (size_t)blk * 1344;
#pragma unroll
        for (int k = 0; k < 6; ++k) {
            int idx = tid + k * 256;
            if (idx < 1344) s4[idx] = g[idx];
        }
        __syncthreads();

        float* sf = (float*)s4;
        float x[NC];
        float S = 0.0f;
#pragma unroll
        for (int c = 0; c < NC; ++c) { x[c] = sf[tid * NC + c]; S += x[c]; }
        float base = Loff * S;
#pragma unroll
        for (int d = 0; d < NC; ++d) sf[tid * NC + d] = fmaf(Ldelta, x[d], base);
        __syncthreads();

        float4* o = (float4*)logits + (size_t)blk * 1344;
#pragma unroll
        for (int k = 0; k < 6; ++k) {
            int idx = tid + k * 256;
            if (idx < 1344) o[idx] = s4[idx];
        }
    }
}

extern "C" void kernel_launch(void* const* d_in, const int* in_sizes, int n_in,
                              void* d_out, int out_size, void* d_ws, size_t ws_size,
                              hipStream_t stream) {
    const float* x0 = (const float*)d_in[0];
    const int*   t  = (const int*)d_in[1];
    float* out    = (float*)d_out;
    float* logits = out;                                // [B,S,C]
    float* qt     = out + (size_t)NB * NS * NC;         // [B,S,C,C]
    float4* ws    = (float4*)d_ws;

    schedule_kernel<<<1, 64, 0, stream>>>(t, ws);
    fused_kernel<<<17408, 256, 0, stream>>>(x0, ws, logits, qt);
}

// Round 5
// 462.983 us; speedup vs baseline: 1.1464x; 1.1464x over previous
//
#include <hip/hip_runtime.h>
#include <math.h>

#define NB 64          // batch
#define NS 4096        // seq
#define NC 21          // classes

typedef float vfloat4 __attribute__((ext_vector_type(4)));

// ONE fused kernel, 5120 blocks x 256.
//   Blocks 0..1023   : logits (256 rows of x0 each, LDS-staged)
//   Blocks 1024..5119: q_t — each writes 4 chunks of 1764 float4.
//     chunk = 1764 float4 = 7056 floats = 16 * 441  → every chunk starts at
//     tile position 0, so a thread's 7-float4 pattern is chunk-invariant:
//     precompute in registers, then 28 back-to-back dwordx4 stores.
// alpha_cumprod telescopes: betas clip only at the final step, so
//   alpha[t] = ac[t+1]/ac[0]          (t <= 198)
//   alpha[199] = 0.001 * ac[199]/ac[0]
// with ac[i] = cos^2( ((i/200)+1e-4)/(1+1e-4) * pi/2 ).  2 cos calls/block.
__global__ __launch_bounds__(256) void fused_kernel(const float* __restrict__ x0,
                                                    const int* __restrict__ t,
                                                    float* __restrict__ logits,
                                                    float* __restrict__ qt) {
    __shared__ float4 s4[1344];   // logits path only (21.5 KB)
    const int tid = threadIdx.x;
    const int id = blockIdx.x;
    const bool is_log = (id < 1024);
    const int b = is_log ? (id >> 4) : ((id - 1024) >> 6);

    const int tb = t[b];                                   // uniform -> s_load
    const float K = 1.5707963267948966f / 1.0001f;         // (pi/2)/(1+1e-4)
    const int ti = (tb >= 199) ? 199 : (tb + 1);
    const float c0 = __cosf(1e-4f * K);
    const float c1 = __cosf(((float)ti * 0.005f + 1e-4f) * K);
    float alpha = (c1 * c1) / (c0 * c0);
    if (tb >= 199) alpha *= 0.001f;
    const float qo = (1.0f - alpha) * (1.0f / 21.0f);
    const float qd = qo + alpha;

    if (!is_log) {
        // ---------------- q_t path: precomputed pattern, pure stores --------
        const int qb = id - 1024;            // 0..4095 ; 64 per batch
        int p = tid * 4;                     // pattern pos of first float4
        if (p >= 882) p -= 882; else if (p >= 441) p -= 441;
        int r = p % 22;                      // diag iff pos % 22 == 0
        vfloat4 vals[7];
#pragma unroll
        for (int k = 0; k < 7; ++k) {
#pragma unroll
            for (int m = 0; m < 4; ++m) {
                const int pm = p + m;
                const int rm = r + m;
                const bool diag = (pm >= 441) ? (pm == 441) : (rm == 0 || rm == 22);
                vals[k][m] = diag ? qd : qo;
            }
            // advance 256 float4 = 1024 floats: +142 (mod 441), +10 (mod 22);
            // the 441-wrap subtracts 441 === 1 (mod 22).
            p += 142; r += 10;
            if (p >= 441) { p -= 441; r -= 1; }
            if (r >= 22) r -= 22;
        }
        vfloat4* dst = (vfloat4*)qt + (size_t)qb * (4 * 1764) + tid;
#pragma unroll
        for (int j = 0; j < 4; ++j) {
#pragma unroll
            for (int k = 0; k < 7; ++k) {
                if (tid + k * 256 < 1764) dst[k * 256] = vals[k];
            }
            dst += 1764;
        }
    } else {
        // ---------------- logits path --------------------------------------
        const float Loff   = logf(qo + 1e-10f);
        const float Ldelta = logf(qd + 1e-10f) - Loff;
        const int blk = id;                  // 0..1023, 256 rows each

        const float4* g = (const float4*)x0 + (size_t)blk * 1344;
#pragma unroll
        for (int k = 0; k < 6; ++k) {
            int idx = tid + k * 256;
            if (idx < 1344) s4[idx] = g[idx];
        }
        __syncthreads();

        float* sf = (float*)s4;
        float x[NC];
        float S = 0.0f;
#pragma unroll
        for (int c = 0; c < NC; ++c) { x[c] = sf[tid * NC + c]; S += x[c]; }
        const float base = Loff * S;
#pragma unroll
        for (int d = 0; d < NC; ++d) sf[tid * NC + d] = fmaf(Ldelta, x[d], base);
        __syncthreads();

        float4* o = (float4*)logits + (size_t)blk * 1344;
#pragma unroll
        for (int k = 0; k < 6; ++k) {
            int idx = tid + k * 256;
            if (idx < 1344) o[idx] = s4[idx];
        }
    }
}

extern "C" void kernel_launch(void* const* d_in, const int* in_sizes, int n_in,
                              void* d_out, int out_size, void* d_ws, size_t ws_size,
                              hipStream_t stream) {
    const float* x0 = (const float*)d_in[0];
    const int*   t  = (const int*)d_in[1];
    float* out    = (float*)d_out;
    float* logits = out;                                // [B,S,C]
    float* qt     = out + (size_t)NB * NS * NC;         // [B,S,C,C]

    fused_kernel<<<5120, 256, 0, stream>>>(x0, t, logits, qt);
}